// Round 1
// baseline (3001.830 us; speedup 1.0000x reference)
//
#include <hip/hip_runtime.h>
#include <math.h>

#define NN  50000
#define FIN 512
#define HH1 500
#define HH2 100
#define NC  16
#define NE  800000

// ---------------- degree / norm ----------------

__global__ void init_deg_k(float* deg) {
    int i = blockIdx.x * blockDim.x + threadIdx.x;
    if (i < NN) deg[i] = 1.0f;   // self-loop contributes 1
}

__global__ void count_deg_k(const int* __restrict__ rows, float* deg) {
    int i = blockIdx.x * blockDim.x + threadIdx.x;
    if (i < NE) atomicAdd(&deg[rows[i]], 1.0f);
}

__global__ void dinv_k(float* deg) {
    int i = blockIdx.x * blockDim.x + threadIdx.x;
    if (i < NN) deg[i] = 1.0f / sqrtf(deg[i]);  // deg >= 1 always (self-loop)
}

// ---------------- dense GEMM: C[n,m] = A[n,k] @ W[k,m] + b ----------------
// 64x64 block tile, 256 threads, 4x4 micro-tile per thread, BK=16.

#define BM 64
#define BN 64
#define BK 16

__global__ __launch_bounds__(256) void gemm_bias_k(
    const float* __restrict__ A, const float* __restrict__ W,
    const float* __restrict__ bias, float* __restrict__ C,
    int n, int k, int m)
{
    __shared__ float As[BK][BM + 1];
    __shared__ float Ws[BK][BN];

    int tid = threadIdx.x;          // 0..255
    int tx = tid & 15;              // 0..15 -> col group
    int ty = tid >> 4;              // 0..15 -> row group
    int row0 = blockIdx.x * BM;
    int col0 = blockIdx.y * BN;

    float acc[4][4] = {};

    for (int kt = 0; kt < k; kt += BK) {
        // A tile: BM x BK (1024 elems, 4 per thread), coalesced over k
        #pragma unroll
        for (int i = 0; i < 4; i++) {
            int idx = tid + i * 256;
            int r  = idx >> 4;       // 0..63
            int kk = idx & 15;
            int gr = row0 + r, gk = kt + kk;
            As[kk][r] = (gr < n && gk < k) ? A[(size_t)gr * k + gk] : 0.0f;
        }
        // W tile: BK x BN (1024 elems), coalesced over m
        #pragma unroll
        for (int i = 0; i < 4; i++) {
            int idx = tid + i * 256;
            int kk = idx >> 6;       // 0..15
            int c  = idx & 63;
            int gk = kt + kk, gc = col0 + c;
            Ws[kk][c] = (gk < k && gc < m) ? W[(size_t)gk * m + gc] : 0.0f;
        }
        __syncthreads();

        #pragma unroll
        for (int kk = 0; kk < BK; kk++) {
            float a[4], w[4];
            #pragma unroll
            for (int i = 0; i < 4; i++) a[i] = As[kk][ty * 4 + i];
            #pragma unroll
            for (int j = 0; j < 4; j++) w[j] = Ws[kk][tx * 4 + j];
            #pragma unroll
            for (int i = 0; i < 4; i++)
                #pragma unroll
                for (int j = 0; j < 4; j++)
                    acc[i][j] += a[i] * w[j];
        }
        __syncthreads();
    }

    #pragma unroll
    for (int i = 0; i < 4; i++) {
        int gr = row0 + ty * 4 + i;
        if (gr >= n) continue;
        #pragma unroll
        for (int j = 0; j < 4; j++) {
            int gc = col0 + tx * 4 + j;
            if (gc < m) C[(size_t)gr * m + gc] = acc[i][j] + bias[gc];
        }
    }
}

// ---------------- SpMM ----------------

// out[r,f] = dinv[r]^2 * h[r,f]   (self-loop term; also initializes out)
__global__ void self_loop_init_k(const float* __restrict__ h,
                                 const float* __restrict__ dinv,
                                 float* __restrict__ out, int m)
{
    long long idx = (long long)blockIdx.x * blockDim.x + threadIdx.x;
    long long tot = (long long)NN * m;
    if (idx >= tot) return;
    int r = (int)(idx / m);
    float d = dinv[r];
    out[idx] = d * d * h[idx];
}

// one wave per edge: out[r,:] += dinv[r]*dinv[c] * h[c,:]
__global__ void spmm_atomic_k(const int* __restrict__ rows,
                              const int* __restrict__ cols,
                              const float* __restrict__ dinv,
                              const float* __restrict__ h,
                              float* __restrict__ out, int m)
{
    int gw   = (int)(((long long)blockIdx.x * blockDim.x + threadIdx.x) >> 6);
    int lane = threadIdx.x & 63;
    if (gw >= NE) return;
    int r = rows[gw], c = cols[gw];
    float w = dinv[r] * dinv[c];
    const float* hrow = h + (size_t)c * m;
    float* orow = out + (size_t)r * m;
    for (int f = lane; f < m; f += 64)
        atomicAdd(&orow[f], w * hrow[f]);
}

__global__ void tanh_k(float* __restrict__ x, long long cnt) {
    long long i = (long long)blockIdx.x * blockDim.x + threadIdx.x;
    if (i < cnt) x[i] = tanhf(x[i]);
}

// final: tanh then softmax over 16 classes, one thread per row
__global__ void tanh_softmax_k(const float* __restrict__ in, float* __restrict__ out) {
    int r = blockIdx.x * blockDim.x + threadIdx.x;
    if (r >= NN) return;
    float v[NC];
    float mx = -1e30f;
    #pragma unroll
    for (int j = 0; j < NC; j++) {
        v[j] = tanhf(in[r * NC + j]);
        mx = fmaxf(mx, v[j]);
    }
    float s = 0.0f;
    #pragma unroll
    for (int j = 0; j < NC; j++) { v[j] = expf(v[j] - mx); s += v[j]; }
    float inv = 1.0f / s;
    #pragma unroll
    for (int j = 0; j < NC; j++) out[r * NC + j] = v[j] * inv;
}

// ---------------- launch ----------------

extern "C" void kernel_launch(void* const* d_in, const int* in_sizes, int n_in,
                              void* d_out, int out_size, void* d_ws, size_t ws_size,
                              hipStream_t stream)
{
    const float* x  = (const float*)d_in[0];
    const int*   ei = (const int*)d_in[1];         // [2, E] int32
    const float* W1 = (const float*)d_in[2];
    const float* b1 = (const float*)d_in[3];
    const float* W2 = (const float*)d_in[4];
    const float* b2 = (const float*)d_in[5];
    const float* W3 = (const float*)d_in[6];
    const float* b3 = (const float*)d_in[7];
    float* out = (float*)d_out;

    const int* rows = ei;
    const int* cols = ei + NE;

    float* dinv = (float*)d_ws;
    float* A = dinv + ((NN + 255) & ~255);          // N x 500 scratch (transform out)
    float* B = A + (size_t)NN * HH1;                // N x 500 scratch (agg out)

    const int T = 256;

    // degree + norm
    init_deg_k<<<(NN + T - 1) / T, T, 0, stream>>>(dinv);
    count_deg_k<<<(NE + T - 1) / T, T, 0, stream>>>(rows, dinv);
    dinv_k<<<(NN + T - 1) / T, T, 0, stream>>>(dinv);

    // ---- layer 1: 512 -> 500
    {
        dim3 g((NN + BM - 1) / BM, (HH1 + BN - 1) / BN);
        gemm_bias_k<<<g, T, 0, stream>>>(x, W1, b1, A, NN, FIN, HH1);
        long long tot = (long long)NN * HH1;
        self_loop_init_k<<<(int)((tot + T - 1) / T), T, 0, stream>>>(A, dinv, B, HH1);
        spmm_atomic_k<<<(NE * 64 + T - 1) / T, T, 0, stream>>>(rows, cols, dinv, A, B, HH1);
        tanh_k<<<(int)((tot + T - 1) / T), T, 0, stream>>>(B, tot);
    }
    // ---- layer 2: 500 -> 100
    {
        dim3 g((NN + BM - 1) / BM, (HH2 + BN - 1) / BN);
        gemm_bias_k<<<g, T, 0, stream>>>(B, W2, b2, A, NN, HH1, HH2);
        long long tot = (long long)NN * HH2;
        self_loop_init_k<<<(int)((tot + T - 1) / T), T, 0, stream>>>(A, dinv, B, HH2);
        spmm_atomic_k<<<(NE * 64 + T - 1) / T, T, 0, stream>>>(rows, cols, dinv, A, B, HH2);
        tanh_k<<<(int)((tot + T - 1) / T), T, 0, stream>>>(B, tot);
    }
    // ---- layer 3: 100 -> 16, then tanh+softmax
    {
        dim3 g((NN + BM - 1) / BM, (NC + BN - 1) / BN);
        gemm_bias_k<<<g, T, 0, stream>>>(B, W3, b3, A, NN, HH2, NC);
        long long tot = (long long)NN * NC;
        self_loop_init_k<<<(int)((tot + T - 1) / T), T, 0, stream>>>(A, dinv, B, NC);
        spmm_atomic_k<<<(NE * 64 + T - 1) / T, T, 0, stream>>>(rows, cols, dinv, A, B, NC);
        tanh_softmax_k<<<(NN + T - 1) / T, T, 0, stream>>>(B, out);
    }
}

// Round 2
// 1396.261 us; speedup vs baseline: 2.1499x; 2.1499x over previous
//
#include <hip/hip_runtime.h>
#include <math.h>

#define NN  50000
#define FIN 512
#define HH1 500
#define HH2 100
#define NC  16
#define NE  800000

// ---------------- CSR build ----------------

__global__ void zero2_k(int* a, int* b) {
    int i = blockIdx.x * blockDim.x + threadIdx.x;
    if (i < NN) { a[i] = 0; b[i] = 0; }
}

__global__ void hist_k(const int* __restrict__ rows, int* __restrict__ rowcnt) {
    int i = blockIdx.x * blockDim.x + threadIdx.x;
    if (i < NE) atomicAdd(&rowcnt[rows[i]], 1);
}

__global__ void dinv_k(const int* __restrict__ rowcnt, float* __restrict__ dinv) {
    int i = blockIdx.x * blockDim.x + threadIdx.x;
    if (i < NN) dinv[i] = rsqrtf((float)(rowcnt[i] + 1));   // +1 self-loop
}

// single-block exclusive scan of rowcnt -> row_ptr (50000 elems, 1024 threads)
__global__ __launch_bounds__(1024) void scan_k(const int* __restrict__ cnt,
                                               int* __restrict__ ptr) {
    __shared__ int s[1024];
    __shared__ int carry;
    int t = threadIdx.x;
    if (t == 0) carry = 0;
    __syncthreads();
    for (int base = 0; base < NN; base += 1024) {
        int i = base + t;
        int v = (i < NN) ? cnt[i] : 0;
        s[t] = v;
        __syncthreads();
        #pragma unroll
        for (int off = 1; off < 1024; off <<= 1) {
            int add = (t >= off) ? s[t - off] : 0;
            __syncthreads();
            s[t] += add;
            __syncthreads();
        }
        int excl = s[t] - v;
        if (i < NN) ptr[i] = carry + excl;
        __syncthreads();
        if (t == 1023) carry += s[1023];
        __syncthreads();
    }
}

__global__ void scatter_k(const int* __restrict__ rows, const int* __restrict__ cols,
                          const float* __restrict__ dinv,
                          const int* __restrict__ row_ptr, int* __restrict__ fill,
                          int* __restrict__ col_s, float* __restrict__ w_s) {
    int e = blockIdx.x * blockDim.x + threadIdx.x;
    if (e >= NE) return;
    int r = rows[e], c = cols[e];
    int pos = row_ptr[r] + atomicAdd(&fill[r], 1);
    col_s[pos] = c;
    w_s[pos] = dinv[r] * dinv[c];
}

// ---------------- dense GEMM: C[n,m] = A[n,k] @ W[k,m] + b ----------------

#define BM 64
#define BN 64
#define BK 16

__global__ __launch_bounds__(256) void gemm_bias_k(
    const float* __restrict__ A, const float* __restrict__ W,
    const float* __restrict__ bias, float* __restrict__ C,
    int n, int k, int m)
{
    __shared__ float As[BK][BM + 1];
    __shared__ float Ws[BK][BN];

    int tid = threadIdx.x;
    int tx = tid & 15;
    int ty = tid >> 4;
    int row0 = blockIdx.x * BM;
    int col0 = blockIdx.y * BN;

    float acc[4][4] = {};

    for (int kt = 0; kt < k; kt += BK) {
        #pragma unroll
        for (int i = 0; i < 4; i++) {
            int idx = tid + i * 256;
            int r  = idx >> 4;
            int kk = idx & 15;
            int gr = row0 + r, gk = kt + kk;
            As[kk][r] = (gr < n && gk < k) ? A[(size_t)gr * k + gk] : 0.0f;
        }
        #pragma unroll
        for (int i = 0; i < 4; i++) {
            int idx = tid + i * 256;
            int kk = idx >> 6;
            int c  = idx & 63;
            int gk = kt + kk, gc = col0 + c;
            Ws[kk][c] = (gk < k && gc < m) ? W[(size_t)gk * m + gc] : 0.0f;
        }
        __syncthreads();

        #pragma unroll
        for (int kk = 0; kk < BK; kk++) {
            float a[4], w[4];
            #pragma unroll
            for (int i = 0; i < 4; i++) a[i] = As[kk][ty * 4 + i];
            #pragma unroll
            for (int j = 0; j < 4; j++) w[j] = Ws[kk][tx * 4 + j];
            #pragma unroll
            for (int i = 0; i < 4; i++)
                #pragma unroll
                for (int j = 0; j < 4; j++)
                    acc[i][j] += a[i] * w[j];
        }
        __syncthreads();
    }

    #pragma unroll
    for (int i = 0; i < 4; i++) {
        int gr = row0 + ty * 4 + i;
        if (gr >= n) continue;
        #pragma unroll
        for (int j = 0; j < 4; j++) {
            int gc = col0 + tx * 4 + j;
            if (gc < m) C[(size_t)gr * m + gc] = acc[i][j] + bias[gc];
        }
    }
}

// ---------------- CSR SpMM, fused self-loop + optional tanh ----------------
// TPR threads per row; NV = float4 per row (NV <= TPR, lane<NV active).
// out[r,:] = act( dinv[r]^2*h[r,:] + sum_j w_j * h[col_j,:] )

template<int TPR, int NV, int ACT>
__global__ __launch_bounds__(256) void spmm_csr_k(
    const int* __restrict__ row_ptr, const int* __restrict__ rowcnt,
    const int* __restrict__ col_s, const float* __restrict__ w_s,
    const float* __restrict__ dinv, const float* __restrict__ h,
    float* __restrict__ out)
{
    const int rpb = 256 / TPR;
    int r = blockIdx.x * rpb + threadIdx.x / TPR;
    int lane = threadIdx.x % TPR;
    if (r >= NN) return;
    bool active = lane < NV;

    const float4* h4 = (const float4*)h;
    float4* o4 = (float4*)out;

    float d = dinv[r];
    float4 acc = make_float4(0.f, 0.f, 0.f, 0.f);
    if (active) {
        float4 v = h4[(size_t)r * NV + lane];
        float w = d * d;
        acc.x = w * v.x; acc.y = w * v.y; acc.z = w * v.z; acc.w = w * v.w;
    }

    int beg = row_ptr[r], cnt = rowcnt[r];
    int j = 0;
    for (; j + 1 < cnt; j += 2) {
        int   c0 = col_s[beg + j],   c1 = col_s[beg + j + 1];
        float w0 = w_s[beg + j],     w1 = w_s[beg + j + 1];
        if (active) {
            float4 v0 = h4[(size_t)c0 * NV + lane];
            float4 v1 = h4[(size_t)c1 * NV + lane];
            acc.x += w0 * v0.x + w1 * v1.x;
            acc.y += w0 * v0.y + w1 * v1.y;
            acc.z += w0 * v0.z + w1 * v1.z;
            acc.w += w0 * v0.w + w1 * v1.w;
        }
    }
    if (j < cnt) {
        int   c0 = col_s[beg + j];
        float w0 = w_s[beg + j];
        if (active) {
            float4 v0 = h4[(size_t)c0 * NV + lane];
            acc.x += w0 * v0.x; acc.y += w0 * v0.y;
            acc.z += w0 * v0.z; acc.w += w0 * v0.w;
        }
    }

    if (active) {
        if (ACT == 1) {
            acc.x = tanhf(acc.x); acc.y = tanhf(acc.y);
            acc.z = tanhf(acc.z); acc.w = tanhf(acc.w);
        }
        o4[(size_t)r * NV + lane] = acc;
    }
}

// final: tanh then softmax over 16 classes, one thread per row
__global__ void tanh_softmax_k(const float* __restrict__ in, float* __restrict__ out) {
    int r = blockIdx.x * blockDim.x + threadIdx.x;
    if (r >= NN) return;
    float v[NC];
    float mx = -1e30f;
    #pragma unroll
    for (int j = 0; j < NC; j++) {
        v[j] = tanhf(in[r * NC + j]);
        mx = fmaxf(mx, v[j]);
    }
    float s = 0.0f;
    #pragma unroll
    for (int j = 0; j < NC; j++) { v[j] = expf(v[j] - mx); s += v[j]; }
    float inv = 1.0f / s;
    #pragma unroll
    for (int j = 0; j < NC; j++) out[r * NC + j] = v[j] * inv;
}

// ---------------- launch ----------------

extern "C" void kernel_launch(void* const* d_in, const int* in_sizes, int n_in,
                              void* d_out, int out_size, void* d_ws, size_t ws_size,
                              hipStream_t stream)
{
    const float* x  = (const float*)d_in[0];
    const int*   ei = (const int*)d_in[1];
    const float* W1 = (const float*)d_in[2];
    const float* b1 = (const float*)d_in[3];
    const float* W2 = (const float*)d_in[4];
    const float* b2 = (const float*)d_in[5];
    const float* W3 = (const float*)d_in[6];
    const float* b3 = (const float*)d_in[7];
    float* out = (float*)d_out;

    const int* rows = ei;
    const int* cols = ei + NE;

    // workspace layout (bytes from d_ws base; all 16B-aligned)
    char* p = (char*)d_ws;
    float* dinv    = (float*)p;            p += (size_t)NN * 4;      // 200000
    int*   rowcnt  = (int*)p;              p += (size_t)NN * 4;
    int*   row_ptr = (int*)p;              p += (size_t)NN * 4;
    int*   fill    = (int*)p;              p += (size_t)NN * 4;
    int*   col_s   = (int*)p;              p += (size_t)NE * 4;
    float* w_s     = (float*)p;            p += (size_t)NE * 4;
    float* A       = (float*)p;            p += (size_t)NN * HH1 * 4;
    float* B       = (float*)p;

    const int T = 256;

    // ---- CSR build + degree norm
    zero2_k<<<(NN + T - 1) / T, T, 0, stream>>>(rowcnt, fill);
    hist_k<<<(NE + T - 1) / T, T, 0, stream>>>(rows, rowcnt);
    dinv_k<<<(NN + T - 1) / T, T, 0, stream>>>(rowcnt, dinv);
    scan_k<<<1, 1024, 0, stream>>>(rowcnt, row_ptr);
    scatter_k<<<(NE + T - 1) / T, T, 0, stream>>>(rows, cols, dinv, row_ptr, fill,
                                                  col_s, w_s);

    // ---- layer 1: 512 -> 500
    {
        dim3 g((NN + BM - 1) / BM, (HH1 + BN - 1) / BN);
        gemm_bias_k<<<g, T, 0, stream>>>(x, W1, b1, A, NN, FIN, HH1);
        // TPR=128, NV=125 (500 floats), fused tanh
        spmm_csr_k<128, 125, 1><<<(NN + 1) / 2, T, 0, stream>>>(
            row_ptr, rowcnt, col_s, w_s, dinv, A, B);
    }
    // ---- layer 2: 500 -> 100
    {
        dim3 g((NN + BM - 1) / BM, (HH2 + BN - 1) / BN);
        gemm_bias_k<<<g, T, 0, stream>>>(B, W2, b2, A, NN, HH1, HH2);
        // TPR=32, NV=25 (100 floats), fused tanh
        spmm_csr_k<32, 25, 1><<<(NN + 7) / 8, T, 0, stream>>>(
            row_ptr, rowcnt, col_s, w_s, dinv, A, B);
    }
    // ---- layer 3: 100 -> 16
    {
        dim3 g((NN + BM - 1) / BM, (NC + BN - 1) / BN);
        gemm_bias_k<<<g, T, 0, stream>>>(B, W3, b3, A, NN, HH2, NC);
        // TPR=4, NV=4 (16 floats), no activation (done in tanh_softmax)
        spmm_csr_k<4, 4, 0><<<(NN + 63) / 64, T, 0, stream>>>(
            row_ptr, rowcnt, col_s, w_s, dinv, A, B);
        tanh_softmax_k<<<(NN + T - 1) / T, T, 0, stream>>>(B, out);
    }
}

// Round 3
// 1264.216 us; speedup vs baseline: 2.3745x; 1.1044x over previous
//
#include <hip/hip_runtime.h>
#include <math.h>

#define NN  50000
#define FIN 512
#define HH1 500
#define HH2 100
#define NC  16
#define NE  800000

// ---------------- CSR build ----------------

__global__ void zero2_k(int* a, int* b) {
    int i = blockIdx.x * blockDim.x + threadIdx.x;
    if (i < NN) { a[i] = 0; b[i] = 0; }
}

__global__ void hist_k(const int* __restrict__ rows, int* __restrict__ rowcnt) {
    int i = blockIdx.x * blockDim.x + threadIdx.x;
    if (i < NE) atomicAdd(&rowcnt[rows[i]], 1);
}

__global__ void dinv_k(const int* __restrict__ rowcnt, float* __restrict__ dinv) {
    int i = blockIdx.x * blockDim.x + threadIdx.x;
    if (i < NN) dinv[i] = rsqrtf((float)(rowcnt[i] + 1));   // +1 self-loop
}

// single-block exclusive scan of rowcnt -> row_ptr
__global__ __launch_bounds__(1024) void scan_k(const int* __restrict__ cnt,
                                               int* __restrict__ ptr) {
    __shared__ int s[1024];
    __shared__ int carry;
    int t = threadIdx.x;
    if (t == 0) carry = 0;
    __syncthreads();
    for (int base = 0; base < NN; base += 1024) {
        int i = base + t;
        int v = (i < NN) ? cnt[i] : 0;
        s[t] = v;
        __syncthreads();
        #pragma unroll
        for (int off = 1; off < 1024; off <<= 1) {
            int add = (t >= off) ? s[t - off] : 0;
            __syncthreads();
            s[t] += add;
            __syncthreads();
        }
        int excl = s[t] - v;
        if (i < NN) ptr[i] = carry + excl;
        __syncthreads();
        if (t == 1023) carry += s[1023];
        __syncthreads();
    }
}

__global__ void scatter_k(const int* __restrict__ rows, const int* __restrict__ cols,
                          const float* __restrict__ dinv,
                          const int* __restrict__ row_ptr, int* __restrict__ fill,
                          int* __restrict__ col_s, float* __restrict__ w_s) {
    int e = blockIdx.x * blockDim.x + threadIdx.x;
    if (e >= NE) return;
    int r = rows[e], c = cols[e];
    int pos = row_ptr[r] + atomicAdd(&fill[r], 1);
    col_s[pos] = c;
    w_s[pos] = dinv[r] * dinv[c];
}

// ---------------- big GEMM: 128x128 tile, BK=32, 8x8 micro ----------------
// W-fragment split into two float4 halves 64 cols apart -> 2-way LDS aliasing (free).

#define GBM 128
#define GBN 128
#define GBK 32

__global__ __launch_bounds__(256, 3) void gemm128_k(
    const float* __restrict__ A, const float* __restrict__ W,
    const float* __restrict__ bias, float* __restrict__ C,
    int n, int k, int m)
{
    __shared__ float As[GBK][GBM + 4];   // k-major (transposed on store)
    __shared__ float Ws[GBK][GBN + 4];   // natural k-major

    int tid = threadIdx.x;
    int tx = tid & 15;        // 0..15 col group
    int ty = tid >> 4;        // 0..15 row group
    int row0 = blockIdx.x * GBM;
    int col0 = blockIdx.y * GBN;

    float acc[8][8] = {};

    int ar = tid >> 3;              // 0..31
    int akc = (tid & 7) * 4;        // 0..28
    int wkk = tid >> 5;             // 0..7
    int wc = (tid & 31) * 4;        // 0..124

    for (int kt = 0; kt < k; kt += GBK) {
        // ---- stage A tile: 128 rows x 32 k, transpose to k-major
        #pragma unroll
        for (int i = 0; i < 4; i++) {
            int rr = ar + i * 32;
            int gr = row0 + rr;
            int gk = kt + akc;
            float4 v = make_float4(0.f, 0.f, 0.f, 0.f);
            if (gr < n) {
                if (gk + 3 < k) {
                    v = *(const float4*)(A + (size_t)gr * k + gk);
                } else {
                    float t0 = (gk + 0 < k) ? A[(size_t)gr * k + gk + 0] : 0.f;
                    float t1 = (gk + 1 < k) ? A[(size_t)gr * k + gk + 1] : 0.f;
                    float t2 = (gk + 2 < k) ? A[(size_t)gr * k + gk + 2] : 0.f;
                    float t3 = (gk + 3 < k) ? A[(size_t)gr * k + gk + 3] : 0.f;
                    v = make_float4(t0, t1, t2, t3);
                }
            }
            As[akc + 0][rr] = v.x;
            As[akc + 1][rr] = v.y;
            As[akc + 2][rr] = v.z;
            As[akc + 3][rr] = v.w;
        }
        // ---- stage W tile: 32 k x 128 cols
        #pragma unroll
        for (int i = 0; i < 4; i++) {
            int kk2 = wkk + i * 8;
            int gk = kt + kk2;
            int gc = col0 + wc;
            float4 v = make_float4(0.f, 0.f, 0.f, 0.f);
            if (gk < k) {
                if (gc + 3 < m) {
                    v = *(const float4*)(W + (size_t)gk * m + gc);
                } else {
                    float t0 = (gc + 0 < m) ? W[(size_t)gk * m + gc + 0] : 0.f;
                    float t1 = (gc + 1 < m) ? W[(size_t)gk * m + gc + 1] : 0.f;
                    float t2 = (gc + 2 < m) ? W[(size_t)gk * m + gc + 2] : 0.f;
                    float t3 = (gc + 3 < m) ? W[(size_t)gk * m + gc + 3] : 0.f;
                    v = make_float4(t0, t1, t2, t3);
                }
            }
            *(float4*)&Ws[kk2][wc] = v;
        }
        __syncthreads();

        #pragma unroll
        for (int kk = 0; kk < GBK; kk++) {
            float4 a0 = *(const float4*)&As[kk][ty * 8];
            float4 a1 = *(const float4*)&As[kk][ty * 8 + 4];
            float4 w0 = *(const float4*)&Ws[kk][tx * 4];
            float4 w1 = *(const float4*)&Ws[kk][64 + tx * 4];
            float a[8] = {a0.x, a0.y, a0.z, a0.w, a1.x, a1.y, a1.z, a1.w};
            float w[8] = {w0.x, w0.y, w0.z, w0.w, w1.x, w1.y, w1.z, w1.w};
            #pragma unroll
            for (int i = 0; i < 8; i++)
                #pragma unroll
                for (int j = 0; j < 8; j++)
                    acc[i][j] += a[i] * w[j];
        }
        __syncthreads();
    }

    // ---- epilogue: cols {col0+4tx+q} and {col0+64+4tx+q}
    #pragma unroll
    for (int i = 0; i < 8; i++) {
        int gr = row0 + ty * 8 + i;
        if (gr >= n) continue;
        int gc0 = col0 + tx * 4;
        int gc1 = col0 + 64 + tx * 4;
        if (gc0 + 3 < m) {
            float4 o = make_float4(acc[i][0] + bias[gc0], acc[i][1] + bias[gc0 + 1],
                                   acc[i][2] + bias[gc0 + 2], acc[i][3] + bias[gc0 + 3]);
            *(float4*)(C + (size_t)gr * m + gc0) = o;
        } else {
            for (int q = 0; q < 4; q++)
                if (gc0 + q < m) C[(size_t)gr * m + gc0 + q] = acc[i][q] + bias[gc0 + q];
        }
        if (gc1 + 3 < m) {
            float4 o = make_float4(acc[i][4] + bias[gc1], acc[i][5] + bias[gc1 + 1],
                                   acc[i][6] + bias[gc1 + 2], acc[i][7] + bias[gc1 + 3]);
            *(float4*)(C + (size_t)gr * m + gc1) = o;
        } else {
            for (int q = 0; q < 4; q++)
                if (gc1 + q < m) C[(size_t)gr * m + gc1 + q] = acc[i][4 + q] + bias[gc1 + q];
        }
    }
}

// ---------------- small GEMM (layer 3): 64x64 tile ----------------

#define BM 64
#define BN 64
#define BK 16

__global__ __launch_bounds__(256) void gemm_bias_k(
    const float* __restrict__ A, const float* __restrict__ W,
    const float* __restrict__ bias, float* __restrict__ C,
    int n, int k, int m)
{
    __shared__ float As[BK][BM + 1];
    __shared__ float Ws[BK][BN];

    int tid = threadIdx.x;
    int tx = tid & 15;
    int ty = tid >> 4;
    int row0 = blockIdx.x * BM;
    int col0 = blockIdx.y * BN;

    float acc[4][4] = {};

    for (int kt = 0; kt < k; kt += BK) {
        #pragma unroll
        for (int i = 0; i < 4; i++) {
            int idx = tid + i * 256;
            int r  = idx >> 4;
            int kk = idx & 15;
            int gr = row0 + r, gk = kt + kk;
            As[kk][r] = (gr < n && gk < k) ? A[(size_t)gr * k + gk] : 0.0f;
        }
        #pragma unroll
        for (int i = 0; i < 4; i++) {
            int idx = tid + i * 256;
            int kk = idx >> 6;
            int c  = idx & 63;
            int gk = kt + kk, gc = col0 + c;
            Ws[kk][c] = (gk < k && gc < m) ? W[(size_t)gk * m + gc] : 0.0f;
        }
        __syncthreads();

        #pragma unroll
        for (int kk = 0; kk < BK; kk++) {
            float a[4], w[4];
            #pragma unroll
            for (int i = 0; i < 4; i++) a[i] = As[kk][ty * 4 + i];
            #pragma unroll
            for (int j = 0; j < 4; j++) w[j] = Ws[kk][tx * 4 + j];
            #pragma unroll
            for (int i = 0; i < 4; i++)
                #pragma unroll
                for (int j = 0; j < 4; j++)
                    acc[i][j] += a[i] * w[j];
        }
        __syncthreads();
    }

    #pragma unroll
    for (int i = 0; i < 4; i++) {
        int gr = row0 + ty * 4 + i;
        if (gr >= n) continue;
        #pragma unroll
        for (int j = 0; j < 4; j++) {
            int gc = col0 + tx * 4 + j;
            if (gc < m) C[(size_t)gr * m + gc] = acc[i][j] + bias[gc];
        }
    }
}

// ---------------- CSR SpMM, fused self-loop + optional tanh ----------------

template<int TPR, int NV, int ACT>
__global__ __launch_bounds__(256) void spmm_csr_k(
    const int* __restrict__ row_ptr, const int* __restrict__ rowcnt,
    const int* __restrict__ col_s, const float* __restrict__ w_s,
    const float* __restrict__ dinv, const float* __restrict__ h,
    float* __restrict__ out)
{
    const int rpb = 256 / TPR;
    int r = blockIdx.x * rpb + threadIdx.x / TPR;
    int lane = threadIdx.x % TPR;
    if (r >= NN) return;
    bool active = lane < NV;

    const float4* h4 = (const float4*)h;
    float4* o4 = (float4*)out;

    float d = dinv[r];
    float4 acc = make_float4(0.f, 0.f, 0.f, 0.f);
    if (active) {
        float4 v = h4[(size_t)r * NV + lane];
        float w = d * d;
        acc.x = w * v.x; acc.y = w * v.y; acc.z = w * v.z; acc.w = w * v.w;
    }

    int beg = row_ptr[r], cnt = rowcnt[r];
    int j = 0;
    for (; j + 1 < cnt; j += 2) {
        int   c0 = col_s[beg + j],   c1 = col_s[beg + j + 1];
        float w0 = w_s[beg + j],     w1 = w_s[beg + j + 1];
        if (active) {
            float4 v0 = h4[(size_t)c0 * NV + lane];
            float4 v1 = h4[(size_t)c1 * NV + lane];
            acc.x += w0 * v0.x + w1 * v1.x;
            acc.y += w0 * v0.y + w1 * v1.y;
            acc.z += w0 * v0.z + w1 * v1.z;
            acc.w += w0 * v0.w + w1 * v1.w;
        }
    }
    if (j < cnt) {
        int   c0 = col_s[beg + j];
        float w0 = w_s[beg + j];
        if (active) {
            float4 v0 = h4[(size_t)c0 * NV + lane];
            acc.x += w0 * v0.x; acc.y += w0 * v0.y;
            acc.z += w0 * v0.z; acc.w += w0 * v0.w;
        }
    }

    if (active) {
        if (ACT == 1) {
            acc.x = tanhf(acc.x); acc.y = tanhf(acc.y);
            acc.z = tanhf(acc.z); acc.w = tanhf(acc.w);
        }
        o4[(size_t)r * NV + lane] = acc;
    }
}

// final: tanh then softmax over 16 classes, one thread per row
__global__ void tanh_softmax_k(const float* __restrict__ in, float* __restrict__ out) {
    int r = blockIdx.x * blockDim.x + threadIdx.x;
    if (r >= NN) return;
    float v[NC];
    float mx = -1e30f;
    #pragma unroll
    for (int j = 0; j < NC; j++) {
        v[j] = tanhf(in[r * NC + j]);
        mx = fmaxf(mx, v[j]);
    }
    float s = 0.0f;
    #pragma unroll
    for (int j = 0; j < NC; j++) { v[j] = expf(v[j] - mx); s += v[j]; }
    float inv = 1.0f / s;
    #pragma unroll
    for (int j = 0; j < NC; j++) out[r * NC + j] = v[j] * inv;
}

// ---------------- launch ----------------

extern "C" void kernel_launch(void* const* d_in, const int* in_sizes, int n_in,
                              void* d_out, int out_size, void* d_ws, size_t ws_size,
                              hipStream_t stream)
{
    const float* x  = (const float*)d_in[0];
    const int*   ei = (const int*)d_in[1];
    const float* W1 = (const float*)d_in[2];
    const float* b1 = (const float*)d_in[3];
    const float* W2 = (const float*)d_in[4];
    const float* b2 = (const float*)d_in[5];
    const float* W3 = (const float*)d_in[6];
    const float* b3 = (const float*)d_in[7];
    float* out = (float*)d_out;

    const int* rows = ei;
    const int* cols = ei + NE;

    char* p = (char*)d_ws;
    float* dinv    = (float*)p;            p += (size_t)NN * 4;
    int*   rowcnt  = (int*)p;              p += (size_t)NN * 4;
    int*   row_ptr = (int*)p;              p += (size_t)NN * 4;
    int*   fill    = (int*)p;              p += (size_t)NN * 4;
    int*   col_s   = (int*)p;              p += (size_t)NE * 4;
    float* w_s     = (float*)p;            p += (size_t)NE * 4;
    float* A       = (float*)p;            p += (size_t)NN * HH1 * 4;
    float* B       = (float*)p;

    const int T = 256;

    // ---- CSR build + degree norm
    zero2_k<<<(NN + T - 1) / T, T, 0, stream>>>(rowcnt, fill);
    hist_k<<<(NE + T - 1) / T, T, 0, stream>>>(rows, rowcnt);
    dinv_k<<<(NN + T - 1) / T, T, 0, stream>>>(rowcnt, dinv);
    scan_k<<<1, 1024, 0, stream>>>(rowcnt, row_ptr);
    scatter_k<<<(NE + T - 1) / T, T, 0, stream>>>(rows, cols, dinv, row_ptr, fill,
                                                  col_s, w_s);

    // ---- layer 1: 512 -> 500
    {
        dim3 g((NN + GBM - 1) / GBM, (HH1 + GBN - 1) / GBN);
        gemm128_k<<<g, T, 0, stream>>>(x, W1, b1, A, NN, FIN, HH1);
        spmm_csr_k<128, 125, 1><<<(NN + 1) / 2, T, 0, stream>>>(
            row_ptr, rowcnt, col_s, w_s, dinv, A, B);
    }
    // ---- layer 2: 500 -> 100
    {
        dim3 g((NN + GBM - 1) / GBM, (HH2 + GBN - 1) / GBN);
        gemm128_k<<<g, T, 0, stream>>>(B, W2, b2, A, NN, HH1, HH2);
        spmm_csr_k<32, 25, 1><<<(NN + 7) / 8, T, 0, stream>>>(
            row_ptr, rowcnt, col_s, w_s, dinv, A, B);
    }
    // ---- layer 3: 100 -> 16
    {
        dim3 g((NN + BM - 1) / BM, (NC + BN - 1) / BN);
        gemm_bias_k<<<g, T, 0, stream>>>(B, W3, b3, A, NN, HH2, NC);
        spmm_csr_k<4, 4, 0><<<(NN + 63) / 64, T, 0, stream>>>(
            row_ptr, rowcnt, col_s, w_s, dinv, A, B);
        tanh_softmax_k<<<(NN + T - 1) / T, T, 0, stream>>>(B, out);
    }
}

// Round 4
// 898.522 us; speedup vs baseline: 3.3409x; 1.4070x over previous
//
#include <hip/hip_runtime.h>
#include <math.h>

#define NN  50000
#define FIN 512
#define HH1 500
#define HH2 100
#define NC  16
#define NE  800000

typedef __attribute__((ext_vector_type(4))) float  f32x4;
typedef __attribute__((ext_vector_type(4))) __bf16 bf16x4;
typedef __attribute__((ext_vector_type(8))) __bf16 bf16x8;

// ---------------- CSR build ----------------

__global__ void zero2_k(int* a, int* b) {
    int i = blockIdx.x * blockDim.x + threadIdx.x;
    if (i < NN) { a[i] = 0; b[i] = 0; }
}

__global__ void hist_k(const int* __restrict__ rows, int* __restrict__ rowcnt) {
    int i = blockIdx.x * blockDim.x + threadIdx.x;
    if (i < NE) atomicAdd(&rowcnt[rows[i]], 1);
}

__global__ void dinv_k(const int* __restrict__ rowcnt, float* __restrict__ dinv) {
    int i = blockIdx.x * blockDim.x + threadIdx.x;
    if (i < NN) dinv[i] = rsqrtf((float)(rowcnt[i] + 1));   // +1 self-loop
}

__global__ __launch_bounds__(1024) void scan_k(const int* __restrict__ cnt,
                                               int* __restrict__ ptr) {
    __shared__ int s[1024];
    __shared__ int carry;
    int t = threadIdx.x;
    if (t == 0) carry = 0;
    __syncthreads();
    for (int base = 0; base < NN; base += 1024) {
        int i = base + t;
        int v = (i < NN) ? cnt[i] : 0;
        s[t] = v;
        __syncthreads();
        #pragma unroll
        for (int off = 1; off < 1024; off <<= 1) {
            int add = (t >= off) ? s[t - off] : 0;
            __syncthreads();
            s[t] += add;
            __syncthreads();
        }
        int excl = s[t] - v;
        if (i < NN) ptr[i] = carry + excl;
        __syncthreads();
        if (t == 1023) carry += s[1023];
        __syncthreads();
    }
}

__global__ void scatter_k(const int* __restrict__ rows, const int* __restrict__ cols,
                          const float* __restrict__ dinv,
                          const int* __restrict__ row_ptr, int* __restrict__ fill,
                          int* __restrict__ col_s, float* __restrict__ w_s) {
    int e = blockIdx.x * blockDim.x + threadIdx.x;
    if (e >= NE) return;
    int r = rows[e], c = cols[e];
    int pos = row_ptr[r] + atomicAdd(&fill[r], 1);
    col_s[pos] = c;
    w_s[pos] = dinv[r] * dinv[c];
}

// ---------------- W pre-transpose + bf16 hi/lo split ----------------
// W[k][m] fp32 -> Wt_hi/Wt_lo [NPAD][512] bf16, zero-padded. KPAD fixed 512.

__global__ void wsplit_k(const float* __restrict__ W, __bf16* __restrict__ Wth,
                         __bf16* __restrict__ Wtl, int k, int m)
{
    int idx = blockIdx.x * 256 + threadIdx.x;   // grid covers NPAD*512 exactly
    int n_ = idx >> 9;
    int kk = idx & 511;
    float v = (kk < k && n_ < m) ? W[(size_t)kk * m + n_] : 0.0f;
    __bf16 h = (__bf16)v;
    Wth[idx] = h;
    Wtl[idx] = (__bf16)(v - (float)h);
}

// ---------------- MFMA GEMM: C = A @ W + b via bf16 hi/lo split ----------------
// 128x128 block tile, BK=32, 4 waves each own a 64x64 quadrant (4x4 tiles of
// 16x16). Per product: ah*bh + ah*bl + al*bh (lo*lo dropped, ~2^-18 rel).
// A frag layout: A[m=lane&15][k=quad*8+j]; B frag: B[k=quad*8+j][n=lane&15];
// C/D: col=lane&15, row=quad*4+reg   (learn_hip m89/m120 verified mappings).

__global__ __launch_bounds__(256) void gemm_mfma_k(
    const float* __restrict__ A, const __bf16* __restrict__ Wth,
    const __bf16* __restrict__ Wtl, const float* __restrict__ bias,
    float* __restrict__ C, int n, int kdim, int m)
{
    __shared__ __align__(16) __bf16 Ahi[128 * 32];
    __shared__ __align__(16) __bf16 Alo[128 * 32];
    __shared__ __align__(16) __bf16 Bhi[128 * 32];
    __shared__ __align__(16) __bf16 Blo[128 * 32];

    int tid  = threadIdx.x;
    int lane = tid & 63;
    int wid  = tid >> 6;
    int wrow = wid & 1, wcol = wid >> 1;
    int lr = lane & 15, q = lane >> 4;
    int row0 = blockIdx.x * 128, col0 = blockIdx.y * 128;

    f32x4 zero = {0.f, 0.f, 0.f, 0.f};
    f32x4 acc[4][4];
    #pragma unroll
    for (int i = 0; i < 4; i++)
        #pragma unroll
        for (int j = 0; j < 4; j++) acc[i][j] = zero;

    for (int kt = 0; kt < kdim; kt += 32) {
        // ---- stage A: 128 rows x 32 k fp32, split to hi/lo bf16 (k-contiguous)
        #pragma unroll
        for (int i = 0; i < 4; i++) {
            int idx = tid + i * 256;
            int rr = idx >> 3, c4 = idx & 7;
            int gr = row0 + rr, gk = kt + c4 * 4;
            float4 v = make_float4(0.f, 0.f, 0.f, 0.f);
            if (gr < n && gk < kdim) v = *(const float4*)(A + (size_t)gr * kdim + gk);
            __bf16 h0 = (__bf16)v.x, h1 = (__bf16)v.y, h2 = (__bf16)v.z, h3 = (__bf16)v.w;
            bf16x4 hv = {h0, h1, h2, h3};
            bf16x4 lv = {(__bf16)(v.x - (float)h0), (__bf16)(v.y - (float)h1),
                         (__bf16)(v.z - (float)h2), (__bf16)(v.w - (float)h3)};
            *(bf16x4*)(Ahi + rr * 32 + c4 * 4) = hv;
            *(bf16x4*)(Alo + rr * 32 + c4 * 4) = lv;
        }
        // ---- stage B: 128 n-rows x 32 k from preconverted Wt (straight copy)
        #pragma unroll
        for (int i = 0; i < 2; i++) {
            int idx = tid + i * 256;
            int rr = idx >> 2, c8 = idx & 3;
            size_t goff = (size_t)(col0 + rr) * 512 + kt + c8 * 8;
            *(bf16x8*)(Bhi + rr * 32 + c8 * 8) = *(const bf16x8*)(Wth + goff);
            *(bf16x8*)(Blo + rr * 32 + c8 * 8) = *(const bf16x8*)(Wtl + goff);
        }
        __syncthreads();

        bf16x8 ah[4], al[4], bh[4], bl[4];
        #pragma unroll
        for (int t = 0; t < 4; t++) {
            int aoff = (wrow * 64 + t * 16 + lr) * 32 + q * 8;
            ah[t] = *(const bf16x8*)(Ahi + aoff);
            al[t] = *(const bf16x8*)(Alo + aoff);
            int boff = (wcol * 64 + t * 16 + lr) * 32 + q * 8;
            bh[t] = *(const bf16x8*)(Bhi + boff);
            bl[t] = *(const bf16x8*)(Blo + boff);
        }
        #pragma unroll
        for (int ti = 0; ti < 4; ti++)
            #pragma unroll
            for (int tj = 0; tj < 4; tj++) {
                acc[ti][tj] = __builtin_amdgcn_mfma_f32_16x16x32_bf16(
                    al[ti], bh[tj], acc[ti][tj], 0, 0, 0);
                acc[ti][tj] = __builtin_amdgcn_mfma_f32_16x16x32_bf16(
                    ah[ti], bl[tj], acc[ti][tj], 0, 0, 0);
                acc[ti][tj] = __builtin_amdgcn_mfma_f32_16x16x32_bf16(
                    ah[ti], bh[tj], acc[ti][tj], 0, 0, 0);
            }
        __syncthreads();
    }

    // ---- epilogue: D col=lane&15, row=quad*4+reg
    #pragma unroll
    for (int ti = 0; ti < 4; ti++) {
        #pragma unroll
        for (int tj = 0; tj < 4; tj++) {
            int col = col0 + wcol * 64 + tj * 16 + lr;
            if (col >= m) continue;
            float bv = bias[col];
            #pragma unroll
            for (int p = 0; p < 4; p++) {
                int row = row0 + wrow * 64 + ti * 16 + q * 4 + p;
                if (row < n) C[(size_t)row * m + col] = acc[ti][tj][p] + bv;
            }
        }
    }
}

// ---------------- small GEMM (layer 3): 64x64 tile fp32 ----------------

#define BM 64
#define BN 64
#define BK 16

__global__ __launch_bounds__(256) void gemm_bias_k(
    const float* __restrict__ A, const float* __restrict__ W,
    const float* __restrict__ bias, float* __restrict__ C,
    int n, int k, int m)
{
    __shared__ float As[BK][BM + 1];
    __shared__ float Ws[BK][BN];

    int tid = threadIdx.x;
    int tx = tid & 15;
    int ty = tid >> 4;
    int row0 = blockIdx.x * BM;
    int col0 = blockIdx.y * BN;

    float acc[4][4] = {};

    for (int kt = 0; kt < k; kt += BK) {
        #pragma unroll
        for (int i = 0; i < 4; i++) {
            int idx = tid + i * 256;
            int r  = idx >> 4;
            int kk = idx & 15;
            int gr = row0 + r, gk = kt + kk;
            As[kk][r] = (gr < n && gk < k) ? A[(size_t)gr * k + gk] : 0.0f;
        }
        #pragma unroll
        for (int i = 0; i < 4; i++) {
            int idx = tid + i * 256;
            int kk = idx >> 6;
            int c  = idx & 63;
            int gk = kt + kk, gc = col0 + c;
            Ws[kk][c] = (gk < k && gc < m) ? W[(size_t)gk * m + gc] : 0.0f;
        }
        __syncthreads();

        #pragma unroll
        for (int kk = 0; kk < BK; kk++) {
            float a[4], w[4];
            #pragma unroll
            for (int i = 0; i < 4; i++) a[i] = As[kk][ty * 4 + i];
            #pragma unroll
            for (int j = 0; j < 4; j++) w[j] = Ws[kk][tx * 4 + j];
            #pragma unroll
            for (int i = 0; i < 4; i++)
                #pragma unroll
                for (int j = 0; j < 4; j++)
                    acc[i][j] += a[i] * w[j];
        }
        __syncthreads();
    }

    #pragma unroll
    for (int i = 0; i < 4; i++) {
        int gr = row0 + ty * 4 + i;
        if (gr >= n) continue;
        #pragma unroll
        for (int j = 0; j < 4; j++) {
            int gc = col0 + tx * 4 + j;
            if (gc < m) C[(size_t)gr * m + gc] = acc[i][j] + bias[gc];
        }
    }
}

// ---------------- CSR SpMM, fused self-loop + optional tanh ----------------

template<int TPR, int NV, int ACT>
__global__ __launch_bounds__(256) void spmm_csr_k(
    const int* __restrict__ row_ptr, const int* __restrict__ rowcnt,
    const int* __restrict__ col_s, const float* __restrict__ w_s,
    const float* __restrict__ dinv, const float* __restrict__ h,
    float* __restrict__ out)
{
    const int rpb = 256 / TPR;
    int r = blockIdx.x * rpb + threadIdx.x / TPR;
    int lane = threadIdx.x % TPR;
    if (r >= NN) return;
    bool active = lane < NV;

    const float4* h4 = (const float4*)h;
    float4* o4 = (float4*)out;

    float d = dinv[r];
    float4 acc = make_float4(0.f, 0.f, 0.f, 0.f);
    if (active) {
        float4 v = h4[(size_t)r * NV + lane];
        float w = d * d;
        acc.x = w * v.x; acc.y = w * v.y; acc.z = w * v.z; acc.w = w * v.w;
    }

    int beg = row_ptr[r], cnt = rowcnt[r];
    int j = 0;
    for (; j + 1 < cnt; j += 2) {
        int   c0 = col_s[beg + j],   c1 = col_s[beg + j + 1];
        float w0 = w_s[beg + j],     w1 = w_s[beg + j + 1];
        if (active) {
            float4 v0 = h4[(size_t)c0 * NV + lane];
            float4 v1 = h4[(size_t)c1 * NV + lane];
            acc.x += w0 * v0.x + w1 * v1.x;
            acc.y += w0 * v0.y + w1 * v1.y;
            acc.z += w0 * v0.z + w1 * v1.z;
            acc.w += w0 * v0.w + w1 * v1.w;
        }
    }
    if (j < cnt) {
        int   c0 = col_s[beg + j];
        float w0 = w_s[beg + j];
        if (active) {
            float4 v0 = h4[(size_t)c0 * NV + lane];
            acc.x += w0 * v0.x; acc.y += w0 * v0.y;
            acc.z += w0 * v0.z; acc.w += w0 * v0.w;
        }
    }

    if (active) {
        if (ACT == 1) {
            acc.x = tanhf(acc.x); acc.y = tanhf(acc.y);
            acc.z = tanhf(acc.z); acc.w = tanhf(acc.w);
        }
        o4[(size_t)r * NV + lane] = acc;
    }
}

// final: tanh then softmax over 16 classes, one thread per row
__global__ void tanh_softmax_k(const float* __restrict__ in, float* __restrict__ out) {
    int r = blockIdx.x * blockDim.x + threadIdx.x;
    if (r >= NN) return;
    float v[NC];
    float mx = -1e30f;
    #pragma unroll
    for (int j = 0; j < NC; j++) {
        v[j] = tanhf(in[r * NC + j]);
        mx = fmaxf(mx, v[j]);
    }
    float s = 0.0f;
    #pragma unroll
    for (int j = 0; j < NC; j++) { v[j] = expf(v[j] - mx); s += v[j]; }
    float inv = 1.0f / s;
    #pragma unroll
    for (int j = 0; j < NC; j++) out[r * NC + j] = v[j] * inv;
}

// ---------------- launch ----------------

extern "C" void kernel_launch(void* const* d_in, const int* in_sizes, int n_in,
                              void* d_out, int out_size, void* d_ws, size_t ws_size,
                              hipStream_t stream)
{
    const float* x  = (const float*)d_in[0];
    const int*   ei = (const int*)d_in[1];
    const float* W1 = (const float*)d_in[2];
    const float* b1 = (const float*)d_in[3];
    const float* W2 = (const float*)d_in[4];
    const float* b2 = (const float*)d_in[5];
    const float* W3 = (const float*)d_in[6];
    const float* b3 = (const float*)d_in[7];
    float* out = (float*)d_out;

    const int* rows = ei;
    const int* cols = ei + NE;

    char* p = (char*)d_ws;
    float*  dinv    = (float*)p;   p += (size_t)NN * 4;
    int*    rowcnt  = (int*)p;     p += (size_t)NN * 4;
    int*    row_ptr = (int*)p;     p += (size_t)NN * 4;
    int*    fill    = (int*)p;     p += (size_t)NN * 4;
    int*    col_s   = (int*)p;     p += (size_t)NE * 4;
    float*  w_s     = (float*)p;   p += (size_t)NE * 4;
    float*  A       = (float*)p;   p += (size_t)NN * HH1 * 4;
    float*  B       = (float*)p;   p += (size_t)NN * HH1 * 4;
    __bf16* Wth1    = (__bf16*)p;  p += (size_t)512 * 512 * 2;
    __bf16* Wtl1    = (__bf16*)p;  p += (size_t)512 * 512 * 2;
    __bf16* Wth2    = (__bf16*)p;  p += (size_t)128 * 512 * 2;
    __bf16* Wtl2    = (__bf16*)p;  p += (size_t)128 * 512 * 2;

    const int T = 256;

    // ---- CSR build + degree norm + weight split (independent preprocessing)
    zero2_k<<<(NN + T - 1) / T, T, 0, stream>>>(rowcnt, fill);
    hist_k<<<(NE + T - 1) / T, T, 0, stream>>>(rows, rowcnt);
    dinv_k<<<(NN + T - 1) / T, T, 0, stream>>>(rowcnt, dinv);
    scan_k<<<1, 1024, 0, stream>>>(rowcnt, row_ptr);
    scatter_k<<<(NE + T - 1) / T, T, 0, stream>>>(rows, cols, dinv, row_ptr, fill,
                                                  col_s, w_s);
    wsplit_k<<<512 * 512 / 256, T, 0, stream>>>(W1, Wth1, Wtl1, FIN, HH1);
    wsplit_k<<<128 * 512 / 256, T, 0, stream>>>(W2, Wth2, Wtl2, HH1, HH2);

    // ---- layer 1: 512 -> 500
    {
        dim3 g((NN + 127) / 128, (HH1 + 127) / 128);
        gemm_mfma_k<<<g, T, 0, stream>>>(x, Wth1, Wtl1, b1, A, NN, FIN, HH1);
        spmm_csr_k<128, 125, 1><<<(NN + 1) / 2, T, 0, stream>>>(
            row_ptr, rowcnt, col_s, w_s, dinv, A, B);
    }
    // ---- layer 2: 500 -> 100
    {
        dim3 g((NN + 127) / 128, 1);
        gemm_mfma_k<<<g, T, 0, stream>>>(B, Wth2, Wtl2, b2, A, NN, HH1, HH2);
        spmm_csr_k<32, 25, 1><<<(NN + 7) / 8, T, 0, stream>>>(
            row_ptr, rowcnt, col_s, w_s, dinv, A, B);
    }
    // ---- layer 3: 100 -> 16
    {
        dim3 g((NN + BM - 1) / BM, (NC + BN - 1) / BN);
        gemm_bias_k<<<g, T, 0, stream>>>(B, W3, b3, A, NN, HH2, NC);
        spmm_csr_k<4, 4, 0><<<(NN + 63) / 64, T, 0, stream>>>(
            row_ptr, rowcnt, col_s, w_s, dinv, A, B);
        tanh_softmax_k<<<(NN + T - 1) / T, T, 0, stream>>>(B, out);
    }
}